// Round 11
// baseline (250.611 us; speedup 1.0000x reference)
//
#include <hip/hip_runtime.h>
#include <hip/hip_bf16.h>

#define N_NODES 50000
#define N_EDGES 800000
#define IN_CH 64
#define HID_CH 128
#define OUT_CH 64
#define N_GRAPHS 512
#define CAP 64         // padded CSR capacity per node (Poisson(16): P(deg>64) ~ e^-42)
#define TN 16          // nodes per stage in node_kernel (50000 % 16 == 0)
#define NPB 64         // nodes per block: grid 782 -> ~3 blocks/CU (was 1.5 at 128)
#define NSTAGE (NPB / TN)

__device__ __forceinline__ void atomAddF(float* p, float v) {
    unsafeAtomicAdd(p, v);  // HW global_atomic_add_f32 on gfx950
}

// ---- Edge phase: direct padded-CSR build (no hist, no scan) + gather ----

// K1: one pass over edges; degi counts, csr16 gets src ids (u16: src < 65536).
__global__ __launch_bounds__(256) void scatter_pad(
    const int* __restrict__ ei, int* __restrict__ degi,
    unsigned short* __restrict__ csr16)
{
    int e = blockIdx.x * 256 + threadIdx.x;
    if (e >= N_EDGES) return;
    int src = ei[e];
    int dst = ei[N_EDGES + e];
    int pos = atomicAdd(&degi[dst], 1);
    csr16[(dst << 6) + pos] = (unsigned short)src;
}

// K2: per-node MEAN gather. One wave per node; 4 lane-groups of 16 process
// 4 neighbors concurrently; 4-deep ILP front, then 2-deep/scalar remainders.
__global__ __launch_bounds__(256) void gather_kernel(
    const float* __restrict__ x, const unsigned short* __restrict__ csr16,
    const int* __restrict__ degi, float* __restrict__ agg)
{
    int wid  = (blockIdx.x * 256 + threadIdx.x) >> 6;
    int lane = threadIdx.x & 63;
    if (wid >= N_NODES) return;
    int d = degi[wid];
    const unsigned short* b = csr16 + ((size_t)wid << 6);
    int g  = lane >> 4;
    int c4 = lane & 15;
    float4 a0 = make_float4(0.f, 0.f, 0.f, 0.f);
    float4 a1 = make_float4(0.f, 0.f, 0.f, 0.f);
    float4 a2 = make_float4(0.f, 0.f, 0.f, 0.f);
    float4 a3 = make_float4(0.f, 0.f, 0.f, 0.f);
    int i = g;
    for (; i + 12 < d; i += 16) {   // 4 independent chains in flight
        int s0 = b[i], s1 = b[i + 4], s2 = b[i + 8], s3 = b[i + 12];
        float4 v0 = *reinterpret_cast<const float4*>(x + (size_t)s0 * IN_CH + c4 * 4);
        float4 v1 = *reinterpret_cast<const float4*>(x + (size_t)s1 * IN_CH + c4 * 4);
        float4 v2 = *reinterpret_cast<const float4*>(x + (size_t)s2 * IN_CH + c4 * 4);
        float4 v3 = *reinterpret_cast<const float4*>(x + (size_t)s3 * IN_CH + c4 * 4);
        a0.x += v0.x; a0.y += v0.y; a0.z += v0.z; a0.w += v0.w;
        a1.x += v1.x; a1.y += v1.y; a1.z += v1.z; a1.w += v1.w;
        a2.x += v2.x; a2.y += v2.y; a2.z += v2.z; a2.w += v2.w;
        a3.x += v3.x; a3.y += v3.y; a3.z += v3.z; a3.w += v3.w;
    }
    for (; i + 4 < d; i += 8) {     // 2-deep remainder
        int s0 = b[i], s1 = b[i + 4];
        float4 v0 = *reinterpret_cast<const float4*>(x + (size_t)s0 * IN_CH + c4 * 4);
        float4 v1 = *reinterpret_cast<const float4*>(x + (size_t)s1 * IN_CH + c4 * 4);
        a0.x += v0.x; a0.y += v0.y; a0.z += v0.z; a0.w += v0.w;
        a1.x += v1.x; a1.y += v1.y; a1.z += v1.z; a1.w += v1.w;
    }
    if (i < d) {
        int s0 = b[i];
        float4 v0 = *reinterpret_cast<const float4*>(x + (size_t)s0 * IN_CH + c4 * 4);
        a0.x += v0.x; a0.y += v0.y; a0.z += v0.z; a0.w += v0.w;
    }
    a0.x += a1.x + a2.x + a3.x; a0.y += a1.y + a2.y + a3.y;
    a0.z += a1.z + a2.z + a3.z; a0.w += a1.w + a2.w + a3.w;
    a0.x += __shfl_xor(a0.x, 16); a0.y += __shfl_xor(a0.y, 16);
    a0.z += __shfl_xor(a0.z, 16); a0.w += __shfl_xor(a0.w, 16);
    a0.x += __shfl_xor(a0.x, 32); a0.y += __shfl_xor(a0.y, 32);
    a0.z += __shfl_xor(a0.z, 32); a0.w += __shfl_xor(a0.w, 32);
    if (g == 0) {
        float inv = 1.0f / fmaxf((float)d, 1.0f);
        a0.x *= inv; a0.y *= inv; a0.z *= inv; a0.w *= inv;
        *reinterpret_cast<float4*>(agg + (size_t)wid * IN_CH + c4 * 4) = a0;
    }
}

// ---- Node phase v5 (r7/r10 proven structure), NPB=64 for 2x occupancy.
// 256 threads = (channel-pair jp=t&63 -> j0=jp, j1=jp+64) x (c-quarter
// q=t>>6). Each feat read feeds TWO channels (8 FMA per ds_read_b128).
// Phase 2 caches relu'd h in the dead feat buffer; phase 3 computes the
// sigmoid per-thread from sred (redundant but barrier-free).
__global__ __launch_bounds__(256, 4) void node_kernel(
    const float* __restrict__ x, const float* __restrict__ agg,
    const int* __restrict__ batch,
    const float* __restrict__ Wl, const float* __restrict__ bl,
    const float* __restrict__ Wr, const float* __restrict__ Watt,
    const float* __restrict__ batt,
    float* __restrict__ pooled, float* __restrict__ counts)
{
    const int t    = threadIdx.x;
    const int jp   = t & 63;    // channel pair: j0=jp, j1=jp+64
    const int q    = t >> 6;    // input-channel quarter
    const int lane = t & 63;

    float4 wl0[4], wl1[4], wr0[4], wr1[4];   // 64 weight floats/thread
#pragma unroll
    for (int c = 0; c < 4; ++c) {
        wl0[c] = *reinterpret_cast<const float4*>(Wl + (size_t)jp * IN_CH + q * 16 + c * 4);
        wr0[c] = *reinterpret_cast<const float4*>(Wr + (size_t)jp * IN_CH + q * 16 + c * 4);
        wl1[c] = *reinterpret_cast<const float4*>(Wl + (size_t)(jp + 64) * IN_CH + q * 16 + c * 4);
        wr1[c] = *reinterpret_cast<const float4*>(Wr + (size_t)(jp + 64) * IN_CH + q * 16 + c * 4);
    }
    const int jj    = t & 127;          // channel for phases 2-3 (t<128)
    const float blj = bl[jj];
    const float wa  = Watt[jj];
    const float ba  = batt[0];

    __shared__ __align__(16) float4 feat[TN][32];   // [node][0-15:x, 16-31:agg]
    float* sh = reinterpret_cast<float*>(feat);     // aliased: h[TN][128] post-GEMV
    __shared__ float psum[4][TN][HID_CH];           // [quarter][node][channel]
    __shared__ float sred[2][TN];

    float accp = 0.f, cnt = 0.f;
    const int nb0 = blockIdx.x * NPB;
    int curb = batch[nb0];

    for (int s = 0; s < NSTAGE; ++s) {
        const int nb = nb0 + s * TN;
        if (nb >= N_NODES) break;   // N_NODES % TN == 0: stages always full
        __syncthreads();            // prev phase-3 readers done (sh, sred)
        // stage 512 float4 (16 nodes x 32 slots), 2 per thread, coalesced
#pragma unroll
        for (int k = 0; k < 2; ++k) {
            int f    = t + k * 256;
            int node = nb + (f >> 5);
            int slot = f & 31;
            const float* src = (slot < 16)
                ? x   + (size_t)node * IN_CH + slot * 4
                : agg + (size_t)node * IN_CH + (slot - 16) * 4;
            feat[f >> 5][slot] = *reinterpret_cast<const float4*>(src);
        }
        __syncthreads();

        // GEMV quarter: psum[q][n][j{0,1}] over this thread's 16 input chans
#pragma unroll
        for (int n = 0; n < TN; ++n) {
            float p0a = 0.f, p0b = 0.f, p1a = 0.f, p1b = 0.f;
#pragma unroll
            for (int c = 0; c < 4; ++c) {
                float4 xv = feat[n][q * 4 + c];        // wave-broadcast
                float4 av = feat[n][16 + q * 4 + c];
                p0a += wr0[c].x * xv.x + wr0[c].y * xv.y
                     + wl0[c].x * av.x + wl0[c].y * av.y;
                p0b += wr0[c].z * xv.z + wr0[c].w * xv.w
                     + wl0[c].z * av.z + wl0[c].w * av.w;
                p1a += wr1[c].x * xv.x + wr1[c].y * xv.y
                     + wl1[c].x * av.x + wl1[c].y * av.y;
                p1b += wr1[c].z * xv.z + wr1[c].w * xv.w
                     + wl1[c].z * av.z + wl1[c].w * av.w;
            }
            psum[q][n][jp]      = p0a + p0b;
            psum[q][n][jp + 64] = p1a + p1b;
        }
        __syncthreads();

        // phase 2: h = relu(sum_q psum + bl); cache h in sh; attention partial
        if (t < 128) {
#pragma unroll
            for (int n = 0; n < TN; ++n) {
                float h = psum[0][n][jj] + psum[1][n][jj]
                        + psum[2][n][jj] + psum[3][n][jj] + blj;
                h = fmaxf(h, 0.f);
                sh[n * HID_CH + jj] = h;
                float r = wa * h;
                r += __shfl_xor(r, 1);  r += __shfl_xor(r, 2);
                r += __shfl_xor(r, 4);  r += __shfl_xor(r, 8);
                r += __shfl_xor(r, 16); r += __shfl_xor(r, 32);
                if (lane == n) sred[t >> 6][n] = r;
            }
        }
        __syncthreads();

        // phase 3: per-thread sigmoid from sred (redundant, barrier-free) +
        // pooled accumulation with batch flush (t<128)
        if (t < 128) {
#pragma unroll
            for (int n = 0; n < TN; ++n) {
                float sc = 1.f / (1.f + expf(-(sred[0][n] + sred[1][n] + ba)));
                float hs = sh[n * HID_CH + jj] * sc;
                int b = batch[nb + n];
                if (b != curb) {
                    atomAddF(&pooled[(size_t)curb * HID_CH + jj], accp);
                    if (jj == 0) atomAddF(&counts[curb], cnt);
                    accp = 0.f; cnt = 0.f; curb = b;
                }
                accp += hs;
                cnt  += 1.f;
            }
        }
    }
    if (t < 128) {
        atomAddF(&pooled[(size_t)curb * HID_CH + jj], accp);
        if (jj == 0) atomAddF(&counts[curb], cnt);
    }
}

// K4: out[g][j] = bout[j] + sum_c Wout[j][c] * pooled_mean[g][c]
__global__ __launch_bounds__(64) void out_kernel(
    const float* __restrict__ pooled, const float* __restrict__ counts,
    const float* __restrict__ Wout, const float* __restrict__ bout,
    float* __restrict__ out)
{
    const int g = blockIdx.x;
    const int j = threadIdx.x;
    __shared__ __align__(16) float sp[HID_CH];
    float inv = 1.0f / fmaxf(counts[g], 1.0f);
    sp[j]      = pooled[(size_t)g * HID_CH + j] * inv;
    sp[j + 64] = pooled[(size_t)g * HID_CH + 64 + j] * inv;
    __syncthreads();
    float acc = bout[j];
#pragma unroll
    for (int c4 = 0; c4 < HID_CH / 4; ++c4) {
        float4 w = *reinterpret_cast<const float4*>(Wout + (size_t)j * HID_CH + c4 * 4);
        acc += w.x * sp[c4 * 4 + 0] + w.y * sp[c4 * 4 + 1]
             + w.z * sp[c4 * 4 + 2] + w.w * sp[c4 * 4 + 3];
    }
    out[(size_t)g * OUT_CH + j] = acc;
}

extern "C" void kernel_launch(void* const* d_in, const int* in_sizes, int n_in,
                              void* d_out, int out_size, void* d_ws, size_t ws_size,
                              hipStream_t stream)
{
    const float* x     = (const float*)d_in[0];
    const int*   ei    = (const int*)d_in[1];
    const int*   batch = (const int*)d_in[2];
    const float* Wl    = (const float*)d_in[3];
    const float* bl    = (const float*)d_in[4];
    const float* Wr    = (const float*)d_in[5];
    const float* Watt  = (const float*)d_in[6];
    const float* batt  = (const float*)d_in[7];
    const float* Wout  = (const float*)d_in[8];
    const float* bout  = (const float*)d_in[9];
    float* out = (float*)d_out;

    // workspace layout: [zeroed | uninitialized]
    int*            degi   = (int*)d_ws;                              // zero
    float*          pooled = (float*)(degi + N_NODES);                // zero
    float*          counts = pooled + (size_t)N_GRAPHS * HID_CH;      // zero
    unsigned short* csr16  = (unsigned short*)(counts + N_GRAPHS);    // written by scatter
    float*          agg    = (float*)(csr16 + (size_t)N_NODES * CAP); // fully overwritten

    size_t zero_bytes = ((size_t)N_NODES
                       + (size_t)N_GRAPHS * HID_CH + N_GRAPHS) * sizeof(int);
    hipMemsetAsync(d_ws, 0, zero_bytes, stream);

    scatter_pad<<<(N_EDGES + 255) / 256, 256, 0, stream>>>(ei, degi, csr16);
    gather_kernel<<<(N_NODES * 64 + 255) / 256, 256, 0, stream>>>(x, csr16, degi, agg);
    node_kernel<<<(N_NODES + NPB - 1) / NPB, 256, 0, stream>>>(
        x, agg, batch, Wl, bl, Wr, Watt, batt, pooled, counts);
    out_kernel<<<N_GRAPHS, 64, 0, stream>>>(pooled, counts, Wout, bout, out);
}

// Round 13
// 244.270 us; speedup vs baseline: 1.0260x; 1.0260x over previous
//
#include <hip/hip_runtime.h>
#include <hip/hip_bf16.h>

#define N_NODES 50000
#define N_EDGES 800000
#define IN_CH 64
#define HID_CH 128
#define OUT_CH 64
#define N_GRAPHS 512
#define CAP 64         // padded CSR capacity per node (Poisson(16): P(deg>64) ~ e^-42)
#define TN 16          // nodes per stage in node_kernel (50000 % 16 == 0)
#define NPB 128        // nodes per block (r10 proven config, 85.6 us)
#define NSTAGE (NPB / TN)

typedef unsigned short ushort_t;
typedef unsigned int uint_t;

__device__ __forceinline__ void atomAddF(float* p, float v) {
    unsafeAtomicAdd(p, v);  // HW global_atomic_add_f32 on gfx950
}

__device__ __forceinline__ ushort_t f2bf(float f) {   // RNE f32->bf16
    uint_t b = __float_as_uint(f);
    return (ushort_t)((b + 0x7fffu + ((b >> 16) & 1u)) >> 16);
}

// ---- Edge phase: padded-CSR build + bf16 row table + mean gather ----

// K0: x -> bf16 table (halves gather's random-row read traffic)
__global__ __launch_bounds__(256) void convert_x(
    const float* __restrict__ x, ushort_t* __restrict__ xh)
{
    int i = blockIdx.x * 256 + threadIdx.x;          // float8 index
    if (i >= N_NODES * IN_CH / 8) return;
    const float4 f0 = *reinterpret_cast<const float4*>(x + (size_t)i * 8);
    const float4 f1 = *reinterpret_cast<const float4*>(x + (size_t)i * 8 + 4);
    uint4 o;
    o.x = (uint_t)f2bf(f0.x) | ((uint_t)f2bf(f0.y) << 16);
    o.y = (uint_t)f2bf(f0.z) | ((uint_t)f2bf(f0.w) << 16);
    o.z = (uint_t)f2bf(f1.x) | ((uint_t)f2bf(f1.y) << 16);
    o.w = (uint_t)f2bf(f1.z) | ((uint_t)f2bf(f1.w) << 16);
    *reinterpret_cast<uint4*>(xh + (size_t)i * 8) = o;
}

// K1: one pass over edges; degi counts, csr16 gets src ids (u16: src < 65536).
__global__ __launch_bounds__(256) void scatter_pad(
    const int* __restrict__ ei, int* __restrict__ degi,
    ushort_t* __restrict__ csr16)
{
    int e = blockIdx.x * 256 + threadIdx.x;
    if (e >= N_EDGES) return;
    int src = ei[e];
    int dst = ei[N_EDGES + e];
    int pos = atomicAdd(&degi[dst], 1);
    csr16[(dst << 6) + pos] = (ushort_t)src;
}

// K2: per-node MEAN gather from the bf16 table. One wave per node;
// 8 lane-groups of 8 process 8 neighbors concurrently (row = 8 lanes x 16B);
// 2 rows in flight per group; f32 accumulate; f32 agg write.
__global__ __launch_bounds__(256) void gather_bf16(
    const ushort_t* __restrict__ xh, const ushort_t* __restrict__ csr16,
    const int* __restrict__ degi, float* __restrict__ agg)
{
    int wid  = (blockIdx.x * 256 + threadIdx.x) >> 6;
    int lane = threadIdx.x & 63;
    if (wid >= N_NODES) return;
    int d = degi[wid];
    const ushort_t* b = csr16 + ((size_t)wid << 6);
    int g  = lane >> 3;   // neighbor group 0..7
    int c8 = lane & 7;    // channel octet: floats c8*8 .. c8*8+7
    float a0[8] = {0.f, 0.f, 0.f, 0.f, 0.f, 0.f, 0.f, 0.f};
    float a1[8] = {0.f, 0.f, 0.f, 0.f, 0.f, 0.f, 0.f, 0.f};
    int i = g;
    for (; i + 8 < d; i += 16) {    // 2 rows in flight
        int s0 = b[i], s1 = b[i + 8];
        uint4 u0 = *reinterpret_cast<const uint4*>(xh + (size_t)s0 * IN_CH + c8 * 8);
        uint4 u1 = *reinterpret_cast<const uint4*>(xh + (size_t)s1 * IN_CH + c8 * 8);
        a0[0] += __uint_as_float(u0.x << 16); a0[1] += __uint_as_float(u0.x & 0xffff0000u);
        a0[2] += __uint_as_float(u0.y << 16); a0[3] += __uint_as_float(u0.y & 0xffff0000u);
        a0[4] += __uint_as_float(u0.z << 16); a0[5] += __uint_as_float(u0.z & 0xffff0000u);
        a0[6] += __uint_as_float(u0.w << 16); a0[7] += __uint_as_float(u0.w & 0xffff0000u);
        a1[0] += __uint_as_float(u1.x << 16); a1[1] += __uint_as_float(u1.x & 0xffff0000u);
        a1[2] += __uint_as_float(u1.y << 16); a1[3] += __uint_as_float(u1.y & 0xffff0000u);
        a1[4] += __uint_as_float(u1.z << 16); a1[5] += __uint_as_float(u1.z & 0xffff0000u);
        a1[6] += __uint_as_float(u1.w << 16); a1[7] += __uint_as_float(u1.w & 0xffff0000u);
    }
    if (i < d) {
        int s0 = b[i];
        uint4 u0 = *reinterpret_cast<const uint4*>(xh + (size_t)s0 * IN_CH + c8 * 8);
        a0[0] += __uint_as_float(u0.x << 16); a0[1] += __uint_as_float(u0.x & 0xffff0000u);
        a0[2] += __uint_as_float(u0.y << 16); a0[3] += __uint_as_float(u0.y & 0xffff0000u);
        a0[4] += __uint_as_float(u0.z << 16); a0[5] += __uint_as_float(u0.z & 0xffff0000u);
        a0[6] += __uint_as_float(u0.w << 16); a0[7] += __uint_as_float(u0.w & 0xffff0000u);
    }
#pragma unroll
    for (int k = 0; k < 8; ++k) {
        a0[k] += a1[k];
        a0[k] += __shfl_xor(a0[k], 8);
        a0[k] += __shfl_xor(a0[k], 16);
        a0[k] += __shfl_xor(a0[k], 32);
    }
    if (g == 0) {
        float inv = 1.0f / fmaxf((float)d, 1.0f);
        float4 w0 = make_float4(a0[0] * inv, a0[1] * inv, a0[2] * inv, a0[3] * inv);
        float4 w1 = make_float4(a0[4] * inv, a0[5] * inv, a0[6] * inv, a0[7] * inv);
        *reinterpret_cast<float4*>(agg + (size_t)wid * IN_CH + c8 * 8)     = w0;
        *reinterpret_cast<float4*>(agg + (size_t)wid * IN_CH + c8 * 8 + 4) = w1;
    }
}

// ---- Node phase v5 (r10 exact, 85.6 us proven): 256 threads =
// (channel-pair jp=t&63 -> j0=jp, j1=jp+64) x (c-quarter q=t>>6).
__global__ __launch_bounds__(256, 4) void node_kernel(
    const float* __restrict__ x, const float* __restrict__ agg,
    const int* __restrict__ batch,
    const float* __restrict__ Wl, const float* __restrict__ bl,
    const float* __restrict__ Wr, const float* __restrict__ Watt,
    const float* __restrict__ batt,
    float* __restrict__ pooled, float* __restrict__ counts)
{
    const int t    = threadIdx.x;
    const int jp   = t & 63;    // channel pair: j0=jp, j1=jp+64
    const int q    = t >> 6;    // input-channel quarter
    const int lane = t & 63;

    float4 wl0[4], wl1[4], wr0[4], wr1[4];   // 64 weight floats/thread
#pragma unroll
    for (int c = 0; c < 4; ++c) {
        wl0[c] = *reinterpret_cast<const float4*>(Wl + (size_t)jp * IN_CH + q * 16 + c * 4);
        wr0[c] = *reinterpret_cast<const float4*>(Wr + (size_t)jp * IN_CH + q * 16 + c * 4);
        wl1[c] = *reinterpret_cast<const float4*>(Wl + (size_t)(jp + 64) * IN_CH + q * 16 + c * 4);
        wr1[c] = *reinterpret_cast<const float4*>(Wr + (size_t)(jp + 64) * IN_CH + q * 16 + c * 4);
    }
    const int jj    = t & 127;          // channel for phases 2-3 (t<128)
    const float blj = bl[jj];
    const float wa  = Watt[jj];
    const float ba  = batt[0];

    __shared__ __align__(16) float4 feat[TN][32];   // [node][0-15:x, 16-31:agg]
    float* sh = reinterpret_cast<float*>(feat);     // aliased: h[TN][128] post-GEMV
    __shared__ float psum[4][TN][HID_CH];           // [quarter][node][channel]
    __shared__ float sred[2][TN];
    __shared__ float ss[TN];

    float accp = 0.f, cnt = 0.f;
    const int nb0 = blockIdx.x * NPB;
    int curb = batch[nb0];

    for (int s = 0; s < NSTAGE; ++s) {
        const int nb = nb0 + s * TN;
        if (nb >= N_NODES) break;   // N_NODES % TN == 0: stages always full
        __syncthreads();            // prev phase-3 readers done (sh, ss)
        // stage 512 float4 (16 nodes x 32 slots), 2 per thread, coalesced
#pragma unroll
        for (int k = 0; k < 2; ++k) {
            int f    = t + k * 256;
            int node = nb + (f >> 5);
            int slot = f & 31;
            const float* src = (slot < 16)
                ? x   + (size_t)node * IN_CH + slot * 4
                : agg + (size_t)node * IN_CH + (slot - 16) * 4;
            feat[f >> 5][slot] = *reinterpret_cast<const float4*>(src);
        }
        __syncthreads();

        // GEMV quarter: psum[q][n][j{0,1}] over this thread's 16 input chans
#pragma unroll
        for (int n = 0; n < TN; ++n) {
            float p0a = 0.f, p0b = 0.f, p1a = 0.f, p1b = 0.f;
#pragma unroll
            for (int c = 0; c < 4; ++c) {
                float4 xv = feat[n][q * 4 + c];        // wave-broadcast
                float4 av = feat[n][16 + q * 4 + c];
                p0a += wr0[c].x * xv.x + wr0[c].y * xv.y
                     + wl0[c].x * av.x + wl0[c].y * av.y;
                p0b += wr0[c].z * xv.z + wr0[c].w * xv.w
                     + wl0[c].z * av.z + wl0[c].w * av.w;
                p1a += wr1[c].x * xv.x + wr1[c].y * xv.y
                     + wl1[c].x * av.x + wl1[c].y * av.y;
                p1b += wr1[c].z * xv.z + wr1[c].w * xv.w
                     + wl1[c].z * av.z + wl1[c].w * av.w;
            }
            psum[q][n][jp]      = p0a + p0b;
            psum[q][n][jp + 64] = p1a + p1b;
        }
        __syncthreads();

        // phase 2: h = relu(sum_q psum + bl); cache h in sh; attention partial
        if (t < 128) {
#pragma unroll
            for (int n = 0; n < TN; ++n) {
                float h = psum[0][n][jj] + psum[1][n][jj]
                        + psum[2][n][jj] + psum[3][n][jj] + blj;
                h = fmaxf(h, 0.f);
                sh[n * HID_CH + jj] = h;
                float r = wa * h;
                r += __shfl_xor(r, 1);  r += __shfl_xor(r, 2);
                r += __shfl_xor(r, 4);  r += __shfl_xor(r, 8);
                r += __shfl_xor(r, 16); r += __shfl_xor(r, 32);
                if (lane == n) sred[t >> 6][n] = r;
            }
        }
        __syncthreads();
        if (t < TN) ss[t] = 1.f / (1.f + expf(-(sred[0][t] + sred[1][t] + ba)));
        __syncthreads();

        // phase 3: pooled accumulation with batch flush (t<128)
        if (t < 128) {
#pragma unroll
            for (int n = 0; n < TN; ++n) {
                float hs = sh[n * HID_CH + jj] * ss[n];
                int b = batch[nb + n];
                if (b != curb) {
                    atomAddF(&pooled[(size_t)curb * HID_CH + jj], accp);
                    if (jj == 0) atomAddF(&counts[curb], cnt);
                    accp = 0.f; cnt = 0.f; curb = b;
                }
                accp += hs;
                cnt  += 1.f;
            }
        }
    }
    if (t < 128) {
        atomAddF(&pooled[(size_t)curb * HID_CH + jj], accp);
        if (jj == 0) atomAddF(&counts[curb], cnt);
    }
}

// K4: out[g][j] = bout[j] + sum_c Wout[j][c] * pooled_mean[g][c]
__global__ __launch_bounds__(64) void out_kernel(
    const float* __restrict__ pooled, const float* __restrict__ counts,
    const float* __restrict__ Wout, const float* __restrict__ bout,
    float* __restrict__ out)
{
    const int g = blockIdx.x;
    const int j = threadIdx.x;
    __shared__ __align__(16) float sp[HID_CH];
    float inv = 1.0f / fmaxf(counts[g], 1.0f);
    sp[j]      = pooled[(size_t)g * HID_CH + j] * inv;
    sp[j + 64] = pooled[(size_t)g * HID_CH + 64 + j] * inv;
    __syncthreads();
    float acc = bout[j];
#pragma unroll
    for (int c4 = 0; c4 < HID_CH / 4; ++c4) {
        float4 w = *reinterpret_cast<const float4*>(Wout + (size_t)j * HID_CH + c4 * 4);
        acc += w.x * sp[c4 * 4 + 0] + w.y * sp[c4 * 4 + 1]
             + w.z * sp[c4 * 4 + 2] + w.w * sp[c4 * 4 + 3];
    }
    out[(size_t)g * OUT_CH + j] = acc;
}

extern "C" void kernel_launch(void* const* d_in, const int* in_sizes, int n_in,
                              void* d_out, int out_size, void* d_ws, size_t ws_size,
                              hipStream_t stream)
{
    const float* x     = (const float*)d_in[0];
    const int*   ei    = (const int*)d_in[1];
    const int*   batch = (const int*)d_in[2];
    const float* Wl    = (const float*)d_in[3];
    const float* bl    = (const float*)d_in[4];
    const float* Wr    = (const float*)d_in[5];
    const float* Watt  = (const float*)d_in[6];
    const float* batt  = (const float*)d_in[7];
    const float* Wout  = (const float*)d_in[8];
    const float* bout  = (const float*)d_in[9];
    float* out = (float*)d_out;

    // workspace layout: [zeroed | uninitialized]
    int*      degi   = (int*)d_ws;                                // zero
    float*    pooled = (float*)(degi + N_NODES);                  // zero
    float*    counts = pooled + (size_t)N_GRAPHS * HID_CH;        // zero
    ushort_t* csr16  = (ushort_t*)(counts + N_GRAPHS);            // written by scatter
    float*    agg    = (float*)(csr16 + (size_t)N_NODES * CAP);   // fully overwritten
    ushort_t* xh     = (ushort_t*)(agg + (size_t)N_NODES * IN_CH);// written by convert

    size_t zero_bytes = ((size_t)N_NODES
                       + (size_t)N_GRAPHS * HID_CH + N_GRAPHS) * sizeof(int);
    hipMemsetAsync(d_ws, 0, zero_bytes, stream);

    convert_x<<<(N_NODES * IN_CH / 8 + 255) / 256, 256, 0, stream>>>(x, xh);
    scatter_pad<<<(N_EDGES + 255) / 256, 256, 0, stream>>>(ei, degi, csr16);
    gather_bf16<<<(N_NODES * 64 + 255) / 256, 256, 0, stream>>>(xh, csr16, degi, agg);
    node_kernel<<<(N_NODES + NPB - 1) / NPB, 256, 0, stream>>>(
        x, agg, batch, Wl, bl, Wr, Watt, batt, pooled, counts);
    out_kernel<<<N_GRAPHS, 64, 0, stream>>>(pooled, counts, Wout, bout, out);
}